// Round 5
// baseline (7079.827 us; speedup 1.0000x reference)
//
#include <hip/hip_runtime.h>
#include <hip/hip_bf16.h>
#include <math.h>

#define U_ 256
#define NN 128
#define MM 64
#define OUT_ 8
#define CLIPV 20.0f
#define IN_DIM_ 9
#define HH 2
#define PER_ 70
#define PP 268
#define PPAD 272
#define B_ 128
#define T_ 130
#define TSTART 65
#define CTRL_ 73
#define KB 80          // padded controller K (rows 73..79 zero)

// ws layout
#define WX_ELEMS (KB*1024)
#define WH_ELEMS (U_*1024)
#define WP_ELEMS (U_*PPAD)
#define WX_OFF  0
#define WH_OFF  (WX_ELEMS*2)
#define WP_OFF  (WH_OFF + WH_ELEMS*2)
#define BLP_OFF (WP_OFF + WP_ELEMS*2)
#define BPP_OFF (BLP_OFF + 1024*4)
#define PREP_TOT (WX_ELEMS + WH_ELEMS + WP_ELEMS + 1024 + PPAD)

__device__ __forceinline__ float sigf(float x){ return 1.0f/(1.0f+expf(-x)); }
__device__ __forceinline__ float splus(float x){ return log1pf(expf(x)); }
__device__ __forceinline__ float clipf(float x){ return fminf(fmaxf(x,-CLIPV),CLIPV); }
__device__ __forceinline__ float blo(unsigned u){ return __uint_as_float(u<<16); }
__device__ __forceinline__ float bhi(unsigned u){ return __uint_as_float(u & 0xffff0000u); }

#define FMA8(u, v) { \
    a0 = fmaf(v, blo(u.x), a0); a1 = fmaf(v, bhi(u.x), a1); \
    a2 = fmaf(v, blo(u.y), a2); a3 = fmaf(v, bhi(u.y), a3); \
    a4 = fmaf(v, blo(u.z), a4); a5 = fmaf(v, bhi(u.z), a5); \
    a6 = fmaf(v, blo(u.w), a6); a7 = fmaf(v, bhi(u.w), a7); }

__global__ void prep_kernel(const float* __restrict__ W_x, const float* __restrict__ W_h,
                            const float* __restrict__ W_p, const float* __restrict__ b_lstm,
                            const float* __restrict__ b_p,
                            __hip_bfloat16* __restrict__ wx, __hip_bfloat16* __restrict__ wh,
                            __hip_bfloat16* __restrict__ wp,
                            float* __restrict__ blp, float* __restrict__ bpp)
{
    for (int idx = blockIdx.x*blockDim.x + threadIdx.x; idx < PREP_TOT; idx += gridDim.x*blockDim.x){
        if (idx < WX_ELEMS){
            int i = idx>>10, jn = idx&1023, u = jn>>2, k = jn&3;
            wx[idx] = __float2bfloat16(i < CTRL_ ? W_x[i*1024 + k*256 + u] : 0.0f);
        } else if (idx < WX_ELEMS + WH_ELEMS){
            int e = idx - WX_ELEMS;
            int i = e>>10, jn = e&1023, u = jn>>2, k = jn&3;
            wh[e] = __float2bfloat16(W_h[i*1024 + k*256 + u]);
        } else if (idx < WX_ELEMS + WH_ELEMS + WP_ELEMS){
            int e = idx - WX_ELEMS - WH_ELEMS;
            int i = e / PPAD, j = e - i*PPAD;
            wp[e] = (j < PP) ? __float2bfloat16(W_p[i*PP + j]) : __float2bfloat16(0.0f);
        } else if (idx < WX_ELEMS + WH_ELEMS + WP_ELEMS + 1024){
            int jn = idx - (WX_ELEMS + WH_ELEMS + WP_ELEMS);
            int u = jn>>2, k = jn&3;
            blp[jn] = b_lstm[k*256 + u];
        } else {
            int j = idx - (WX_ELEMS + WH_ELEMS + WP_ELEMS + 1024);
            bpp[j] = (j < PP) ? b_p[j] : 0.0f;
        }
    }
}

__global__ __launch_bounds__(1024,1) void ntm_kernel(
    const float* __restrict__ inputs,
    const float* __restrict__ W_o, const float* __restrict__ b_o,
    const float* __restrict__ r0, const float* __restrict__ w0,
    const __hip_bfloat16* __restrict__ wx, const __hip_bfloat16* __restrict__ wh,
    const __hip_bfloat16* __restrict__ wp,
    const float* __restrict__ blp, const float* __restrict__ bpp,
    float* __restrict__ out)
{
    const int b = blockIdx.x;
    const int t = threadIdx.x;
    const int wv = t >> 6, ln = t & 63;

    __shared__ float Mem[NN][MM+1];
    __shared__ float hbuf[U_], cbuf[U_];
    __shared__ float gpart[4*U_];     // h@W_h (permuted cols), one step ahead
    __shared__ float xr[KB];          // [x_t(9); r_{t-1}(64); 0-pad(7)]
    __shared__ float jpart[OUT_];
    __shared__ float kv[HH][MM];
    __shared__ float ebuf[MM], abuf[MM];
    __shared__ float scal[12];        // 0,1 beta; 2,3 g; 4,5 gamma; 6..11 s
    __shared__ float innr[HH][NN];
    __shared__ float Mn[NN];
    __shared__ float wgs[HH][NN];
    __shared__ float wtab[HH][NN];    // w (serves as both cur and prev)
    __shared__ float rpart[16][MM];

    // ---- init ----
    for (int idx=t; idx<NN*MM; idx+=1024){ Mem[idx>>6][idx&63] = 1e-6f; }
    gpart[t] = 0.f;
    if (t < NN) Mn[t] = sqrtf((float)MM * 1e-6f * 1e-6f);
    if (t < U_){ hbuf[t]=0.f; cbuf[t]=0.f; }
    if (t < IN_DIM_) xr[t] = inputs[b*T_*IN_DIM_ + t];
    else if (t < CTRL_) xr[t] = tanhf(r0[t-IN_DIM_]);
    else if (t < KB) xr[t] = 0.f;
    if (t >= 128 && t < 256){  // wtab = softmax(w0)
        int h = (t-128)>>6, l = t&63;
        float v0 = w0[h*NN + l], v1 = w0[h*NN + l + 64];
        float mx = fmaxf(v0,v1);
        for (int off=32; off>=1; off>>=1) mx = fmaxf(mx, __shfl_xor(mx, off));
        float e0 = expf(v0-mx), e1 = expf(v1-mx);
        float s = e0+e1;
        for (int off=32; off>=1; off>>=1) s += __shfl_xor(s, off);
        wtab[h][l] = e0/s; wtab[h][l+64] = e1/s;
    }
    __syncthreads();

    for (int step=0; step<T_; ++step){
        // B: gates = xr@Wx + gpart + blp, fused LSTM (permuted unit-major layout)
        {
            const int grp = t>>3, q = t&7, j0 = grp*8;
            const int k0 = q*10;
            const __hip_bfloat16* wb = wx + (k0<<10) + j0;
            uint4 u0 = *(const uint4*)(wb);
            uint4 u1 = *(const uint4*)(wb + 1024);
            uint4 u2 = *(const uint4*)(wb + 2048);
            uint4 u3 = *(const uint4*)(wb + 3072);
            uint4 u4 = *(const uint4*)(wb + 4096);
            uint4 u5 = *(const uint4*)(wb + 5120);
            uint4 u6 = *(const uint4*)(wb + 6144);
            uint4 u7 = *(const uint4*)(wb + 7168);
            uint4 u8 = *(const uint4*)(wb + 8192);
            uint4 u9 = *(const uint4*)(wb + 9216);
            float2 x0 = *(const float2*)&xr[k0];
            float2 x1 = *(const float2*)&xr[k0+2];
            float2 x2 = *(const float2*)&xr[k0+4];
            float2 x3 = *(const float2*)&xr[k0+6];
            float2 x4 = *(const float2*)&xr[k0+8];
            float a0=0.f,a1=0.f,a2=0.f,a3=0.f,a4=0.f,a5=0.f,a6=0.f,a7=0.f;
            FMA8(u0, x0.x); FMA8(u1, x0.y); FMA8(u2, x1.x); FMA8(u3, x1.y);
            FMA8(u4, x2.x); FMA8(u5, x2.y); FMA8(u6, x3.x); FMA8(u7, x3.y);
            FMA8(u8, x4.x); FMA8(u9, x4.y);
            #pragma unroll
            for (int m=1; m<8; m<<=1){
                a0 += __shfl_xor(a0,m); a1 += __shfl_xor(a1,m);
                a2 += __shfl_xor(a2,m); a3 += __shfl_xor(a3,m);
                a4 += __shfl_xor(a4,m); a5 += __shfl_xor(a5,m);
                a6 += __shfl_xor(a6,m); a7 += __shfl_xor(a7,m);
            }
            if (q==0){
                float4 bb0 = *(const float4*)(blp + j0);
                float4 bb1 = *(const float4*)(blp + j0 + 4);
                float4 g0 = *(const float4*)(gpart + j0);
                float4 g1 = *(const float4*)(gpart + j0 + 4);
                const int u = grp*2;
                {
                    float gi=a0+bb0.x+g0.x, gf=a1+bb0.y+g0.y, gg=a2+bb0.z+g0.z, go=a3+bb0.w+g0.w;
                    float c = sigf(gf)*cbuf[u] + sigf(gi)*tanhf(gg);
                    cbuf[u] = c; hbuf[u] = sigf(go)*tanhf(c);
                }
                {
                    float gi=a4+bb1.x+g1.x, gf=a5+bb1.y+g1.y, gg=a6+bb1.z+g1.z, go=a7+bb1.w+g1.w;
                    float c = sigf(gf)*cbuf[u+1] + sigf(gi)*tanhf(gg);
                    cbuf[u+1] = c; hbuf[u+1] = sigf(go)*tanhf(c);
                }
            }
        }
        __syncthreads();

        // FUSED: gpart (next step), params+decode, input prefetch, jpart
        if (t < 512){
            const int grp = t>>2, q = t&3, j0 = grp*8;
            const int k0 = q*64;
            float a0=0.f,a1=0.f,a2=0.f,a3=0.f,a4=0.f,a5=0.f,a6=0.f,a7=0.f;
            #pragma unroll 2
            for (int bk=0; bk<8; ++bk){
                const int ib = k0 + bk*8;
                const __hip_bfloat16* wb = wh + (ib<<10) + j0;
                uint4 u0 = *(const uint4*)(wb);
                uint4 u1 = *(const uint4*)(wb + 1024);
                uint4 u2 = *(const uint4*)(wb + 2048);
                uint4 u3 = *(const uint4*)(wb + 3072);
                uint4 u4 = *(const uint4*)(wb + 4096);
                uint4 u5 = *(const uint4*)(wb + 5120);
                uint4 u6 = *(const uint4*)(wb + 6144);
                uint4 u7 = *(const uint4*)(wb + 7168);
                float4 h0 = *(const float4*)&hbuf[ib];
                float4 h1 = *(const float4*)&hbuf[ib+4];
                FMA8(u0, h0.x); FMA8(u1, h0.y); FMA8(u2, h0.z); FMA8(u3, h0.w);
                FMA8(u4, h1.x); FMA8(u5, h1.y); FMA8(u6, h1.z); FMA8(u7, h1.w);
            }
            #pragma unroll
            for (int m=1; m<4; m<<=1){
                a0 += __shfl_xor(a0,m); a1 += __shfl_xor(a1,m);
                a2 += __shfl_xor(a2,m); a3 += __shfl_xor(a3,m);
                a4 += __shfl_xor(a4,m); a5 += __shfl_xor(a5,m);
                a6 += __shfl_xor(a6,m); a7 += __shfl_xor(a7,m);
            }
            if (q==0){
                *(float4*)&gpart[j0]   = make_float4(a0,a1,a2,a3);
                *(float4*)&gpart[j0+4] = make_float4(a4,a5,a6,a7);
            }
        } else if (t < 784){
            const int tt = t-512, grp = tt>>3, q = tt&7, j0 = grp*8;
            const int k0 = q*32;
            float a0=0.f,a1=0.f,a2=0.f,a3=0.f,a4=0.f,a5=0.f,a6=0.f,a7=0.f;
            #pragma unroll 2
            for (int bk=0; bk<4; ++bk){
                const int ib = k0 + bk*8;
                const __hip_bfloat16* wb = wp + ib*PPAD + j0;
                uint4 u0 = *(const uint4*)(wb);
                uint4 u1 = *(const uint4*)(wb + PPAD);
                uint4 u2 = *(const uint4*)(wb + 2*PPAD);
                uint4 u3 = *(const uint4*)(wb + 3*PPAD);
                uint4 u4 = *(const uint4*)(wb + 4*PPAD);
                uint4 u5 = *(const uint4*)(wb + 5*PPAD);
                uint4 u6 = *(const uint4*)(wb + 6*PPAD);
                uint4 u7 = *(const uint4*)(wb + 7*PPAD);
                float4 h0 = *(const float4*)&hbuf[ib];
                float4 h1 = *(const float4*)&hbuf[ib+4];
                FMA8(u0, h0.x); FMA8(u1, h0.y); FMA8(u2, h0.z); FMA8(u3, h0.w);
                FMA8(u4, h1.x); FMA8(u5, h1.y); FMA8(u6, h1.z); FMA8(u7, h1.w);
            }
            #pragma unroll
            for (int m=1; m<8; m<<=1){
                a0 += __shfl_xor(a0,m); a1 += __shfl_xor(a1,m);
                a2 += __shfl_xor(a2,m); a3 += __shfl_xor(a3,m);
                a4 += __shfl_xor(a4,m); a5 += __shfl_xor(a5,m);
                a6 += __shfl_xor(a6,m); a7 += __shfl_xor(a7,m);
            }
            if (q==0){
                float4 b0 = *(const float4*)(bpp + j0);
                float4 b1 = *(const float4*)(bpp + j0 + 4);
                float pv0=clipf(a0+b0.x), pv1=clipf(a1+b0.y), pv2=clipf(a2+b0.z), pv3=clipf(a3+b0.w);
                float pv4=clipf(a4+b1.x), pv5=clipf(a5+b1.y), pv6=clipf(a6+b1.z), pv7=clipf(a7+b1.w);
                float pv[8] = {pv0,pv1,pv2,pv3,pv4,pv5,pv6,pv7};
                #pragma unroll
                for (int jj=0; jj<8; ++jj){
                    const int j = j0+jj; const float p = pv[jj];
                    if (j < 64) kv[0][j] = tanhf(p);
                    else if (j >= 70 && j < 134) kv[1][j-70] = tanhf(p);
                    else if (j >= 140 && j < 204) ebuf[j-140] = sigf(p);
                    else if (j >= 204 && j < 268) abuf[j-204] = tanhf(p);
                }
                if (j0 == 64){
                    scal[0] = splus(pv0); scal[2] = sigf(pv1);
                    float mx = fmaxf(pv2, fmaxf(pv3, pv4));
                    float e0=expf(pv2-mx), e1=expf(pv3-mx), e2=expf(pv4-mx);
                    float s = e0+e1+e2;
                    scal[6]=e0/s; scal[7]=e1/s; scal[8]=e2/s;
                    scal[4] = 1.f + splus(pv5);
                } else if (j0 == 128){
                    scal[1] = splus(pv6); scal[3] = sigf(pv7);
                } else if (j0 == 136){
                    float mx = fmaxf(pv0, fmaxf(pv1, pv2));
                    float e0=expf(pv0-mx), e1=expf(pv1-mx), e2=expf(pv2-mx);
                    float s = e0+e1+e2;
                    scal[9]=e0/s; scal[10]=e1/s; scal[11]=e2/s;
                    scal[5] = 1.f + splus(pv3);
                }
            }
        } else if (t >= 784 && t < 784+IN_DIM_){
            if (step+1 < T_) xr[t-784] = inputs[(b*T_ + step+1)*IN_DIM_ + (t-784)];
        } else if (t >= 896){
            const int o = (t-896)>>4, l16 = t&15;
            float s = 0.f;
            #pragma unroll
            for (int j=0; j<16; ++j){
                const int i = l16 + (j<<4);
                s = fmaf(hbuf[i], W_o[i*OUT_ + o], s);
            }
            s += __shfl_xor(s,1); s += __shfl_xor(s,2);
            s += __shfl_xor(s,4); s += __shfl_xor(s,8);
            if (l16==0) jpart[o] = s;
        }
        __syncthreads();

        // F: inner products (all 1024 threads, 4-way m split)
        {
            const int h = t>>9, n = (t>>2)&127, q = t&3, m0 = q*16;
            float s = 0.f;
            #pragma unroll 8
            for (int m=m0; m<m0+16; ++m) s = fmaf(kv[h][m], Mem[n][m], s);
            s += __shfl_xor(s,1); s += __shfl_xor(s,2);
            if (q==0) innr[h][n] = s;
        }
        __syncthreads();

        // G: key norm + content softmax + interp + shift + sharpen (2 waves)
        if (t < 128){
            const int h = t>>6, l = ln;
            float kvl = kv[h][l];
            float kn2 = kvl*kvl;
            for (int off=32; off>=1; off>>=1) kn2 += __shfl_xor(kn2, off);
            float kn = sqrtf(kn2);
            float beta = scal[h], g = scal[2+h];
            float bk0 = beta * innr[h][l]   /(kn*Mn[l]   +1e-8f);
            float bk1 = beta * innr[h][l+64]/(kn*Mn[l+64]+1e-8f);
            float mx = fmaxf(bk0,bk1);
            for (int off=32; off>=1; off>>=1) mx = fmaxf(mx, __shfl_xor(mx, off));
            float e0=expf(bk0-mx), e1=expf(bk1-mx);
            float s=e0+e1;
            for (int off=32; off>=1; off>>=1) s += __shfl_xor(s, off);
            float wc0=e0/s, wc1=e1/s;
            wgs[h][l]    = g*wc0 + (1.f-g)*wtab[h][l];
            wgs[h][l+64] = g*wc1 + (1.f-g)*wtab[h][l+64];
            float gamma = scal[4+h];
            float s0=scal[6+3*h], s1=scal[7+3*h], s2=scal[8+3*h];
            const int n0=l, n1=l+64;
            float wt0 = s0*wgs[h][(n0+1)&127] + s1*wgs[h][n0] + s2*wgs[h][(n0+127)&127];
            float wt1 = s0*wgs[h][(n1+1)&127] + s1*wgs[h][n1] + s2*wgs[h][(n1+127)&127];
            float wp0 = powf(wt0, gamma), wp1 = powf(wt1, gamma);
            float ss = wp0+wp1;
            for (int off=32; off>=1; off>>=1) ss += __shfl_xor(ss, off);
            float inv = 1.0f/(ss+1e-8f);
            wtab[h][n0] = wp0*inv; wtab[h][n1] = wp1*inv;
        }
        __syncthreads();

        // H: memory write + row norms + fused read-head partials
        {
            const float el = ebuf[ln], al = abuf[ln];
            const int n0 = wv*8;
            float racc = 0.f;
            #pragma unroll
            for (int k=0; k<8; ++k){
                const int n = n0+k;
                float ww = wtab[1][n];
                float wr = wtab[0][n];
                float v = Mem[n][ln]*(1.0f - ww*el) + ww*al;
                Mem[n][ln] = v;
                racc = fmaf(wr, v, racc);
                float sq = v*v;
                for (int off=32; off>=1; off>>=1) sq += __shfl_xor(sq, off);
                if (ln==0) Mn[n] = sqrtf(sq);
            }
            rpart[wv][ln] = racc;
        }
        __syncthreads();

        // J: r finalize + output (8 waves, one per output)
        if (t < 512){
            const int o = wv;
            float rm = 0.f;
            #pragma unroll
            for (int k=0; k<16; ++k) rm += rpart[k][ln];
            if (o==0) xr[IN_DIM_ + ln] = rm;
            float s = rm * W_o[(U_+ln)*OUT_ + o];
            for (int off=32; off>=1; off>>=1) s += __shfl_xor(s, off);
            if (ln==0 && step>=TSTART){
                float logit = clipf(s + jpart[o] + b_o[o]);
                out[((b*(T_-TSTART)) + (step-TSTART))*OUT_ + o] = sigf(logit);
            }
        }
        __syncthreads();
    }
}

extern "C" void kernel_launch(void* const* d_in, const int* in_sizes, int n_in,
                              void* d_out, int out_size, void* d_ws, size_t ws_size,
                              hipStream_t stream) {
    const float* inputs = (const float*)d_in[0];
    const float* W_x    = (const float*)d_in[1];
    const float* W_h    = (const float*)d_in[2];
    const float* b_lstm = (const float*)d_in[3];
    const float* W_p    = (const float*)d_in[4];
    const float* b_p    = (const float*)d_in[5];
    const float* W_o    = (const float*)d_in[6];
    const float* b_o    = (const float*)d_in[7];
    const float* r0     = (const float*)d_in[8];
    const float* w0     = (const float*)d_in[9];
    float* out = (float*)d_out;

    char* ws = (char*)d_ws;
    __hip_bfloat16* wx = (__hip_bfloat16*)(ws + WX_OFF);
    __hip_bfloat16* wh = (__hip_bfloat16*)(ws + WH_OFF);
    __hip_bfloat16* wp = (__hip_bfloat16*)(ws + WP_OFF);
    float* blp         = (float*)(ws + BLP_OFF);
    float* bpp         = (float*)(ws + BPP_OFF);

    prep_kernel<<<512, 256, 0, stream>>>(W_x, W_h, W_p, b_lstm, b_p, wx, wh, wp, blp, bpp);
    ntm_kernel<<<B_, 1024, 0, stream>>>(inputs, W_o, b_o, r0, w0, wx, wh, wp, blp, bpp, out);
}

// Round 6
// 4171.828 us; speedup vs baseline: 1.6971x; 1.6971x over previous
//
#include <hip/hip_runtime.h>
#include <hip/hip_bf16.h>
#include <math.h>

#define U_ 256
#define NN 128
#define MM 64
#define OUT_ 8
#define CLIPV 20.0f
#define IN_DIM_ 9
#define HH 2
#define PER_ 70
#define PP 268
#define PPAD 272
#define B_ 128
#define T_ 130
#define TSTART 65
#define CTRL_ 73
#define KB 80          // padded controller K (rows 73..79 zero)

// ws layout
#define WX_ELEMS (KB*1024)
#define WH_ELEMS (U_*1024)
#define WP_ELEMS (U_*PPAD)
#define WX_OFF  0
#define WH_OFF  (WX_ELEMS*2)
#define WP_OFF  (WH_OFF + WH_ELEMS*2)
#define BLP_OFF (WP_OFF + WP_ELEMS*2)
#define BPP_OFF (BLP_OFF + 1024*4)
#define PREP_TOT (WX_ELEMS + WH_ELEMS + WP_ELEMS + 1024 + PPAD)

__device__ __forceinline__ float sigf(float x){ return 1.0f/(1.0f+expf(-x)); }
__device__ __forceinline__ float splus(float x){ return log1pf(expf(x)); }
__device__ __forceinline__ float clipf(float x){ return fminf(fmaxf(x,-CLIPV),CLIPV); }
__device__ __forceinline__ float blo(unsigned u){ return __uint_as_float(u<<16); }
__device__ __forceinline__ float bhi(unsigned u){ return __uint_as_float(u & 0xffff0000u); }

#define FMA8(u, v) { \
    a0 = fmaf(v, blo(u.x), a0); a1 = fmaf(v, bhi(u.x), a1); \
    a2 = fmaf(v, blo(u.y), a2); a3 = fmaf(v, bhi(u.y), a3); \
    a4 = fmaf(v, blo(u.z), a4); a5 = fmaf(v, bhi(u.z), a5); \
    a6 = fmaf(v, blo(u.w), a6); a7 = fmaf(v, bhi(u.w), a7); }

__global__ void prep_kernel(const float* __restrict__ W_x, const float* __restrict__ W_h,
                            const float* __restrict__ W_p, const float* __restrict__ b_lstm,
                            const float* __restrict__ b_p,
                            __hip_bfloat16* __restrict__ wx, __hip_bfloat16* __restrict__ wh,
                            __hip_bfloat16* __restrict__ wp,
                            float* __restrict__ blp, float* __restrict__ bpp)
{
    for (int idx = blockIdx.x*blockDim.x + threadIdx.x; idx < PREP_TOT; idx += gridDim.x*blockDim.x){
        if (idx < WX_ELEMS){
            int i = idx>>10, jn = idx&1023, u = jn>>2, k = jn&3;
            wx[idx] = __float2bfloat16(i < CTRL_ ? W_x[i*1024 + k*256 + u] : 0.0f);
        } else if (idx < WX_ELEMS + WH_ELEMS){
            int e = idx - WX_ELEMS;
            int i = e>>10, jn = e&1023, u = jn>>2, k = jn&3;
            wh[e] = __float2bfloat16(W_h[i*1024 + k*256 + u]);
        } else if (idx < WX_ELEMS + WH_ELEMS + WP_ELEMS){
            int e = idx - WX_ELEMS - WH_ELEMS;
            int i = e / PPAD, j = e - i*PPAD;
            wp[e] = (j < PP) ? __float2bfloat16(W_p[i*PP + j]) : __float2bfloat16(0.0f);
        } else if (idx < WX_ELEMS + WH_ELEMS + WP_ELEMS + 1024){
            int jn = idx - (WX_ELEMS + WH_ELEMS + WP_ELEMS);
            int u = jn>>2, k = jn&3;
            blp[jn] = b_lstm[k*256 + u];
        } else {
            int j = idx - (WX_ELEMS + WH_ELEMS + WP_ELEMS + 1024);
            bpp[j] = (j < PP) ? b_p[j] : 0.0f;
        }
    }
}

__global__ __launch_bounds__(1024,1) void ntm_kernel(
    const float* __restrict__ inputs,
    const float* __restrict__ W_o, const float* __restrict__ b_o,
    const float* __restrict__ r0, const float* __restrict__ w0,
    const __hip_bfloat16* __restrict__ wx, const __hip_bfloat16* __restrict__ wh,
    const __hip_bfloat16* __restrict__ wp,
    const float* __restrict__ blp, const float* __restrict__ bpp,
    float* __restrict__ out)
{
    const int b = blockIdx.x;
    const int t = threadIdx.x;
    const int wv = t >> 6, ln = t & 63;

    __shared__ float Mem[NN][MM+1];
    __shared__ float hbuf[U_], cbuf[U_];
    __shared__ float gpart[4*U_];     // h@W_h (permuted cols), one step ahead
    __shared__ float xr[KB];          // [x_t(9); r_{t-1}(64); 0-pad(7)]
    __shared__ float jpart[OUT_];
    __shared__ float kv[HH][MM];
    __shared__ float ebuf[MM], abuf[MM];
    __shared__ float scal[12];        // 0,1 beta; 2,3 g; 4,5 gamma; 6..11 s
    __shared__ float innr[HH][NN];
    __shared__ float Mn[NN];
    __shared__ float wgs[HH][NN];
    __shared__ float wtab[HH][NN];    // w (cur == prev)
    __shared__ float rpart[16][MM];

    // ---- init ----
    for (int idx=t; idx<NN*MM; idx+=1024){ Mem[idx>>6][idx&63] = 1e-6f; }
    gpart[t] = 0.f;
    if (t < NN) Mn[t] = sqrtf((float)MM * 1e-6f * 1e-6f);
    if (t < U_){ hbuf[t]=0.f; cbuf[t]=0.f; }
    if (t < IN_DIM_) xr[t] = inputs[b*T_*IN_DIM_ + t];
    else if (t < CTRL_) xr[t] = tanhf(r0[t-IN_DIM_]);
    else if (t < KB) xr[t] = 0.f;
    if (t >= 128 && t < 256){  // wtab = softmax(w0)
        int h = (t-128)>>6, l = t&63;
        float v0 = w0[h*NN + l], v1 = w0[h*NN + l + 64];
        float mx = fmaxf(v0,v1);
        for (int off=32; off>=1; off>>=1) mx = fmaxf(mx, __shfl_xor(mx, off));
        float e0 = expf(v0-mx), e1 = expf(v1-mx);
        float s = e0+e1;
        for (int off=32; off>=1; off>>=1) s += __shfl_xor(s, off);
        wtab[h][l] = e0/s; wtab[h][l+64] = e1/s;
    }
    __syncthreads();

    for (int step=0; step<T_; ++step){
        // B: gates = xr@Wx + gpart + blp, fused LSTM (permuted unit-major layout)
        {
            const int grp = t>>3, q = t&7, j0 = grp*8;
            const int k0 = q*10;
            const __hip_bfloat16* wb = wx + (k0<<10) + j0;
            float a0=0.f,a1=0.f,a2=0.f,a3=0.f,a4=0.f,a5=0.f,a6=0.f,a7=0.f;
            #pragma unroll 5
            for (int r=0; r<10; ++r){
                float v = xr[k0+r];
                uint4 u = *(const uint4*)(wb + (r<<10));
                FMA8(u, v);
            }
            #pragma unroll
            for (int m=1; m<8; m<<=1){
                a0 += __shfl_xor(a0,m); a1 += __shfl_xor(a1,m);
                a2 += __shfl_xor(a2,m); a3 += __shfl_xor(a3,m);
                a4 += __shfl_xor(a4,m); a5 += __shfl_xor(a5,m);
                a6 += __shfl_xor(a6,m); a7 += __shfl_xor(a7,m);
            }
            if (q==0){
                float4 bb0 = *(const float4*)(blp + j0);
                float4 bb1 = *(const float4*)(blp + j0 + 4);
                float4 g0 = *(const float4*)(gpart + j0);
                float4 g1 = *(const float4*)(gpart + j0 + 4);
                const int u = grp*2;
                {
                    float gi=a0+bb0.x+g0.x, gf=a1+bb0.y+g0.y, gg=a2+bb0.z+g0.z, go=a3+bb0.w+g0.w;
                    float c = sigf(gf)*cbuf[u] + sigf(gi)*tanhf(gg);
                    cbuf[u] = c; hbuf[u] = sigf(go)*tanhf(c);
                }
                {
                    float gi=a4+bb1.x+g1.x, gf=a5+bb1.y+g1.y, gg=a6+bb1.z+g1.z, go=a7+bb1.w+g1.w;
                    float c = sigf(gf)*cbuf[u+1] + sigf(gi)*tanhf(gg);
                    cbuf[u+1] = c; hbuf[u+1] = sigf(go)*tanhf(c);
                }
            }
        }
        __syncthreads();

        // FUSED: gpart (next step), params+decode, input prefetch, jpart
        if (t < 512){
            const int grp = t>>2, q = t&3, j0 = grp*8;
            const int k0 = q*64;
            float a0=0.f,a1=0.f,a2=0.f,a3=0.f,a4=0.f,a5=0.f,a6=0.f,a7=0.f;
            #pragma unroll 4
            for (int i=k0; i<k0+64; ++i){
                float v = hbuf[i];
                uint4 u = *(const uint4*)(wh + (i<<10) + j0);
                FMA8(u, v);
            }
            #pragma unroll
            for (int m=1; m<4; m<<=1){
                a0 += __shfl_xor(a0,m); a1 += __shfl_xor(a1,m);
                a2 += __shfl_xor(a2,m); a3 += __shfl_xor(a3,m);
                a4 += __shfl_xor(a4,m); a5 += __shfl_xor(a5,m);
                a6 += __shfl_xor(a6,m); a7 += __shfl_xor(a7,m);
            }
            if (q==0){
                *(float4*)&gpart[j0]   = make_float4(a0,a1,a2,a3);
                *(float4*)&gpart[j0+4] = make_float4(a4,a5,a6,a7);
            }
        } else if (t < 784){
            const int tt = t-512, grp = tt>>3, q = tt&7, j0 = grp*8;
            const int k0 = q*32;
            float a0=0.f,a1=0.f,a2=0.f,a3=0.f,a4=0.f,a5=0.f,a6=0.f,a7=0.f;
            #pragma unroll 4
            for (int i=k0; i<k0+32; ++i){
                float v = hbuf[i];
                uint4 u = *(const uint4*)(wp + i*PPAD + j0);
                FMA8(u, v);
            }
            #pragma unroll
            for (int m=1; m<8; m<<=1){
                a0 += __shfl_xor(a0,m); a1 += __shfl_xor(a1,m);
                a2 += __shfl_xor(a2,m); a3 += __shfl_xor(a3,m);
                a4 += __shfl_xor(a4,m); a5 += __shfl_xor(a5,m);
                a6 += __shfl_xor(a6,m); a7 += __shfl_xor(a7,m);
            }
            if (q==0){
                float4 b0 = *(const float4*)(bpp + j0);
                float4 b1 = *(const float4*)(bpp + j0 + 4);
                float pv0=clipf(a0+b0.x), pv1=clipf(a1+b0.y), pv2=clipf(a2+b0.z), pv3=clipf(a3+b0.w);
                float pv4=clipf(a4+b1.x), pv5=clipf(a5+b1.y), pv6=clipf(a6+b1.z), pv7=clipf(a7+b1.w);
                float pv[8] = {pv0,pv1,pv2,pv3,pv4,pv5,pv6,pv7};
                #pragma unroll
                for (int jj=0; jj<8; ++jj){
                    const int j = j0+jj; const float p = pv[jj];
                    if (j < 64) kv[0][j] = tanhf(p);
                    else if (j >= 70 && j < 134) kv[1][j-70] = tanhf(p);
                    else if (j >= 140 && j < 204) ebuf[j-140] = sigf(p);
                    else if (j >= 204 && j < 268) abuf[j-204] = tanhf(p);
                }
                if (j0 == 64){
                    scal[0] = splus(pv0); scal[2] = sigf(pv1);
                    float mx = fmaxf(pv2, fmaxf(pv3, pv4));
                    float e0=expf(pv2-mx), e1=expf(pv3-mx), e2=expf(pv4-mx);
                    float s = e0+e1+e2;
                    scal[6]=e0/s; scal[7]=e1/s; scal[8]=e2/s;
                    scal[4] = 1.f + splus(pv5);
                } else if (j0 == 128){
                    scal[1] = splus(pv6); scal[3] = sigf(pv7);
                } else if (j0 == 136){
                    float mx = fmaxf(pv0, fmaxf(pv1, pv2));
                    float e0=expf(pv0-mx), e1=expf(pv1-mx), e2=expf(pv2-mx);
                    float s = e0+e1+e2;
                    scal[9]=e0/s; scal[10]=e1/s; scal[11]=e2/s;
                    scal[5] = 1.f + splus(pv3);
                }
            }
        } else if (t >= 784 && t < 784+IN_DIM_){
            if (step+1 < T_) xr[t-784] = inputs[(b*T_ + step+1)*IN_DIM_ + (t-784)];
        } else if (t >= 896){
            const int o = (t-896)>>4, l16 = t&15;
            float s = 0.f;
            #pragma unroll
            for (int j=0; j<16; ++j){
                const int i = l16 + (j<<4);
                s = fmaf(hbuf[i], W_o[i*OUT_ + o], s);
            }
            s += __shfl_xor(s,1); s += __shfl_xor(s,2);
            s += __shfl_xor(s,4); s += __shfl_xor(s,8);
            if (l16==0) jpart[o] = s;
        }
        __syncthreads();

        // F: inner products (all 1024 threads, 4-way m split)
        {
            const int h = t>>9, n = (t>>2)&127, q = t&3, m0 = q*16;
            float s = 0.f;
            #pragma unroll 8
            for (int m=m0; m<m0+16; ++m) s = fmaf(kv[h][m], Mem[n][m], s);
            s += __shfl_xor(s,1); s += __shfl_xor(s,2);
            if (q==0) innr[h][n] = s;
        }
        __syncthreads();

        // G: key norm + content softmax + interp + shift + sharpen (2 waves)
        if (t < 128){
            const int h = t>>6, l = ln;
            float kvl = kv[h][l];
            float kn2 = kvl*kvl;
            for (int off=32; off>=1; off>>=1) kn2 += __shfl_xor(kn2, off);
            float kn = sqrtf(kn2);
            float beta = scal[h], g = scal[2+h];
            float bk0 = beta * innr[h][l]   /(kn*Mn[l]   +1e-8f);
            float bk1 = beta * innr[h][l+64]/(kn*Mn[l+64]+1e-8f);
            float mx = fmaxf(bk0,bk1);
            for (int off=32; off>=1; off>>=1) mx = fmaxf(mx, __shfl_xor(mx, off));
            float e0=expf(bk0-mx), e1=expf(bk1-mx);
            float s=e0+e1;
            for (int off=32; off>=1; off>>=1) s += __shfl_xor(s, off);
            float wc0=e0/s, wc1=e1/s;
            wgs[h][l]    = g*wc0 + (1.f-g)*wtab[h][l];
            wgs[h][l+64] = g*wc1 + (1.f-g)*wtab[h][l+64];
            float gamma = scal[4+h];
            float s0=scal[6+3*h], s1=scal[7+3*h], s2=scal[8+3*h];
            const int n0=l, n1=l+64;
            float wt0 = s0*wgs[h][(n0+1)&127] + s1*wgs[h][n0] + s2*wgs[h][(n0+127)&127];
            float wt1 = s0*wgs[h][(n1+1)&127] + s1*wgs[h][n1] + s2*wgs[h][(n1+127)&127];
            float wp0 = powf(wt0, gamma), wp1 = powf(wt1, gamma);
            float ss = wp0+wp1;
            for (int off=32; off>=1; off>>=1) ss += __shfl_xor(ss, off);
            float inv = 1.0f/(ss+1e-8f);
            wtab[h][n0] = wp0*inv; wtab[h][n1] = wp1*inv;
        }
        __syncthreads();

        // H: memory write + row norms + fused read-head partials
        {
            const float el = ebuf[ln], al = abuf[ln];
            const int n0 = wv*8;
            float racc = 0.f;
            #pragma unroll
            for (int k=0; k<8; ++k){
                const int n = n0+k;
                float ww = wtab[1][n];
                float wr = wtab[0][n];
                float v = Mem[n][ln]*(1.0f - ww*el) + ww*al;
                Mem[n][ln] = v;
                racc = fmaf(wr, v, racc);
                float sq = v*v;
                for (int off=32; off>=1; off>>=1) sq += __shfl_xor(sq, off);
                if (ln==0) Mn[n] = sqrtf(sq);
            }
            rpart[wv][ln] = racc;
        }
        __syncthreads();

        // J: r finalize + output (8 waves, one per output)
        if (t < 512){
            const int o = wv;
            float rm = 0.f;
            #pragma unroll
            for (int k=0; k<16; ++k) rm += rpart[k][ln];
            if (o==0) xr[IN_DIM_ + ln] = rm;
            float s = rm * W_o[(U_+ln)*OUT_ + o];
            for (int off=32; off>=1; off>>=1) s += __shfl_xor(s, off);
            if (ln==0 && step>=TSTART){
                float logit = clipf(s + jpart[o] + b_o[o]);
                out[((b*(T_-TSTART)) + (step-TSTART))*OUT_ + o] = sigf(logit);
            }
        }
        __syncthreads();
    }
}

extern "C" void kernel_launch(void* const* d_in, const int* in_sizes, int n_in,
                              void* d_out, int out_size, void* d_ws, size_t ws_size,
                              hipStream_t stream) {
    const float* inputs = (const float*)d_in[0];
    const float* W_x    = (const float*)d_in[1];
    const float* W_h    = (const float*)d_in[2];
    const float* b_lstm = (const float*)d_in[3];
    const float* W_p    = (const float*)d_in[4];
    const float* b_p    = (const float*)d_in[5];
    const float* W_o    = (const float*)d_in[6];
    const float* b_o    = (const float*)d_in[7];
    const float* r0     = (const float*)d_in[8];
    const float* w0     = (const float*)d_in[9];
    float* out = (float*)d_out;

    char* ws = (char*)d_ws;
    __hip_bfloat16* wx = (__hip_bfloat16*)(ws + WX_OFF);
    __hip_bfloat16* wh = (__hip_bfloat16*)(ws + WH_OFF);
    __hip_bfloat16* wp = (__hip_bfloat16*)(ws + WP_OFF);
    float* blp         = (float*)(ws + BLP_OFF);
    float* bpp         = (float*)(ws + BPP_OFF);

    prep_kernel<<<512, 256, 0, stream>>>(W_x, W_h, W_p, b_lstm, b_p, wx, wh, wp, blp, bpp);
    ntm_kernel<<<B_, 1024, 0, stream>>>(inputs, W_o, b_o, r0, w0, wx, wh, wp, blp, bpp, out);
}

// Round 7
// 3873.291 us; speedup vs baseline: 1.8279x; 1.0771x over previous
//
#include <hip/hip_runtime.h>
#include <math.h>

typedef _Float16 h2_t __attribute__((ext_vector_type(2)));

#define U_ 256
#define NN 128
#define MM 64
#define OUT_ 8
#define CLIPV 20.0f
#define IN_DIM_ 9
#define HH 2
#define PP 268
#define PPAD 272
#define B_ 128
#define T_ 130
#define TSTART 65
#define CTRL_ 73

// half2-element counts
#define WX2_H2 (40*1024)      // 40 K-pairs x 1024 cols (unit-major)
#define WH2_H2 (128*1024)     // 128 K-pairs x 1024 cols
#define WP2_H2 (128*PPAD)     // 128 K-pairs x 272 cols
// byte offsets in ws
#define WX2_OFF 0
#define WH2_OFF (WX2_H2*4)
#define WP2_OFF (WH2_OFF + WH2_H2*4)
#define BLP_OFF (WP2_OFF + WP2_H2*4)
#define BPP_OFF (BLP_OFF + 1024*4)
#define PREP_TOT (WX2_H2 + WH2_H2 + WP2_H2 + 1024 + PPAD)

__device__ __forceinline__ float sigf(float x){ return 1.0f/(1.0f+__expf(-x)); }
__device__ __forceinline__ float splus(float x){ return log1pf(__expf(x)); }
__device__ __forceinline__ float clipf(float x){ return fminf(fmaxf(x,-CLIPV),CLIPV); }

#if defined(__has_builtin)
#if __has_builtin(__builtin_amdgcn_fdot2)
#define DOT2(a,b,c) __builtin_amdgcn_fdot2((a),(b),(c),false)
#endif
#endif
#ifndef DOT2
#define DOT2(a,b,c) fmaf((float)(a).x,(float)(b).x, fmaf((float)(a).y,(float)(b).y,(c)))
#endif

#define DOT2X4(uu, xv) { \
    a0 = DOT2(xv, __builtin_bit_cast(h2_t, uu.x), a0); \
    a1 = DOT2(xv, __builtin_bit_cast(h2_t, uu.y), a1); \
    a2 = DOT2(xv, __builtin_bit_cast(h2_t, uu.z), a2); \
    a3 = DOT2(xv, __builtin_bit_cast(h2_t, uu.w), a3); }

__global__ void prep_kernel(const float* __restrict__ W_x, const float* __restrict__ W_h,
                            const float* __restrict__ W_p, const float* __restrict__ b_lstm,
                            const float* __restrict__ b_p,
                            h2_t* __restrict__ wx2, h2_t* __restrict__ wh2,
                            h2_t* __restrict__ wp2,
                            float* __restrict__ blp, float* __restrict__ bpp)
{
    for (int idx = blockIdx.x*blockDim.x + threadIdx.x; idx < PREP_TOT; idx += gridDim.x*blockDim.x){
        if (idx < WX2_H2){
            // ctrl order: [r(0..63) -> W_x rows 9+i ; x(64..72) -> rows i-64 ; pad]
            int p = idx>>10, jn = idx&1023, u = jn>>2, k = jn&3, c = k*256+u;
            int i0 = 2*p, i1 = 2*p+1;
            float f0 = (i0<64) ? W_x[(9+i0)*1024+c] : (i0<CTRL_ ? W_x[(i0-64)*1024+c] : 0.f);
            float f1 = (i1<64) ? W_x[(9+i1)*1024+c] : (i1<CTRL_ ? W_x[(i1-64)*1024+c] : 0.f);
            h2_t v; v.x = (_Float16)f0; v.y = (_Float16)f1;
            wx2[idx] = v;
        } else if (idx < WX2_H2 + WH2_H2){
            int e = idx - WX2_H2;
            int p = e>>10, jn = e&1023, u = jn>>2, k = jn&3, c = k*256+u;
            h2_t v; v.x = (_Float16)W_h[(2*p)*1024+c]; v.y = (_Float16)W_h[(2*p+1)*1024+c];
            wh2[e] = v;
        } else if (idx < WX2_H2 + WH2_H2 + WP2_H2){
            int e = idx - WX2_H2 - WH2_H2;
            int p = e / PPAD, j = e - p*PPAD;
            float f0 = (j<PP) ? W_p[(2*p)*PP + j] : 0.f;
            float f1 = (j<PP) ? W_p[(2*p+1)*PP + j] : 0.f;
            h2_t v; v.x = (_Float16)f0; v.y = (_Float16)f1;
            wp2[e] = v;
        } else if (idx < WX2_H2 + WH2_H2 + WP2_H2 + 1024){
            int jn = idx - (WX2_H2 + WH2_H2 + WP2_H2);
            int u = jn>>2, k = jn&3;
            blp[jn] = b_lstm[k*256 + u];
        } else {
            int j = idx - (WX2_H2 + WH2_H2 + WP2_H2 + 1024);
            bpp[j] = (j < PP) ? b_p[j] : 0.0f;
        }
    }
}

__global__ __launch_bounds__(1024,1) void ntm_kernel(
    const float* __restrict__ inputs,
    const float* __restrict__ W_o, const float* __restrict__ b_o,
    const float* __restrict__ r0, const float* __restrict__ w0,
    const h2_t* __restrict__ wx2, const h2_t* __restrict__ wh2,
    const h2_t* __restrict__ wp2,
    const float* __restrict__ blp, const float* __restrict__ bpp,
    float* __restrict__ out)
{
    const int b = blockIdx.x;
    const int t = threadIdx.x;
    const int wv = t >> 6, ln = t & 63;

    __shared__ float Mem[NN][MM+1];
    __shared__ float hbuf[U_], cbuf[U_];
    __shared__ float gpart[4*U_];      // h@W_h (unit-major), one step ahead
    __shared__ h2_t  xr2[40];          // packed ctrl: [r(32 pairs); x(5 pairs); 0-pad(3)]
    __shared__ h2_t  hb2[U_/2];        // h as f16 pairs
    __shared__ float jpart[OUT_];
    __shared__ float kv[HH][MM];
    __shared__ float ebuf[MM], abuf[MM];
    __shared__ float prmS[12];         // raw scalar params: head0 j64..69, head1 j134..139
    __shared__ float scal[12];         // 0,1 beta; 2,3 g; 4,5 gamma; 6..11 s
    __shared__ float innr[HH][NN];
    __shared__ float Mn[NN];
    __shared__ float wgs[HH][NN];
    __shared__ float wtab[HH][NN];     // w (cur == prev)
    __shared__ float rpart[16][MM];

    _Float16* hbh = (_Float16*)hb2;

    // ---- init ----
    for (int idx=t; idx<NN*MM; idx+=1024){ Mem[idx>>6][idx&63] = 1e-6f; }
    gpart[t & 1023] = 0.f;
    if (t < NN) Mn[t] = sqrtf((float)MM * 1e-6f * 1e-6f);
    if (t < U_){ hbuf[t]=0.f; cbuf[t]=0.f; }
    if (t < U_/2){ h2_t z; z.x=(_Float16)0.f; z.y=(_Float16)0.f; hb2[t]=z; }
    if (t >= 256 && t < 296){
        int p = t-256;
        h2_t v;
        if (p < 32){ v.x = (_Float16)tanhf(r0[2*p]); v.y = (_Float16)tanhf(r0[2*p+1]); }
        else if (p < 37){
            int e0 = 2*(p-32), e1 = e0+1;
            float f0 = (e0<IN_DIM_) ? inputs[b*T_*IN_DIM_ + e0] : 0.f;
            float f1 = (e1<IN_DIM_) ? inputs[b*T_*IN_DIM_ + e1] : 0.f;
            v.x = (_Float16)f0; v.y = (_Float16)f1;
        } else { v.x=(_Float16)0.f; v.y=(_Float16)0.f; }
        xr2[p] = v;
    }
    if (t >= 128 && t < 256){  // wtab = softmax(w0)
        int h = (t-128)>>6, l = t&63;
        float v0 = w0[h*NN + l], v1 = w0[h*NN + l + 64];
        float mx = fmaxf(v0,v1);
        for (int off=32; off>=1; off>>=1) mx = fmaxf(mx, __shfl_xor(mx, off));
        float e0 = __expf(v0-mx), e1 = __expf(v1-mx);
        float s = e0+e1;
        for (int off=32; off>=1; off>>=1) s += __shfl_xor(s, off);
        wtab[h][l] = e0/s; wtab[h][l+64] = e1/s;
    }
    __syncthreads();

    for (int step=0; step<T_; ++step){
        // B: gates = ctrl@Wx + gpart + blp, fused LSTM (unit-major; colgrp 4 = one unit)
        {
            const int u = t>>2, q = t&3, j0 = u*4;
            const int k0 = q*10;
            const h2_t* wb = wx2 + (k0<<10) + j0;
            float a0=0.f,a1=0.f,a2=0.f,a3=0.f;
            #pragma unroll 5
            for (int p=0; p<10; ++p){
                h2_t xv = xr2[k0+p];
                uint4 uu = *(const uint4*)(wb + (p<<10));
                DOT2X4(uu, xv);
            }
            a0 += __shfl_xor(a0,1); a1 += __shfl_xor(a1,1);
            a2 += __shfl_xor(a2,1); a3 += __shfl_xor(a3,1);
            a0 += __shfl_xor(a0,2); a1 += __shfl_xor(a1,2);
            a2 += __shfl_xor(a2,2); a3 += __shfl_xor(a3,2);
            if (q==0){
                float4 bb = *(const float4*)(blp + j0);
                float4 g0 = *(const float4*)(gpart + j0);
                float gi=a0+bb.x+g0.x, gf=a1+bb.y+g0.y, gg=a2+bb.z+g0.z, go=a3+bb.w+g0.w;
                float c = sigf(gf)*cbuf[u] + sigf(gi)*tanhf(gg);
                cbuf[u] = c;
                float h = sigf(go)*tanhf(c);
                hbuf[u] = h; hbh[u] = (_Float16)h;
            }
        }
        __syncthreads();

        // FUSED: gpart (all threads) ; then params / Mn / x-prefetch / jpart subsets
        {
            const int u = t>>2, q = t&3, j0 = u*4;
            const int k0 = q*32;
            const h2_t* wb = wh2 + (k0<<10) + j0;
            float a0=0.f,a1=0.f,a2=0.f,a3=0.f;
            #pragma unroll 4
            for (int p=0; p<32; ++p){
                h2_t hv = hb2[k0+p];
                uint4 uu = *(const uint4*)(wb + (p<<10));
                DOT2X4(uu, hv);
            }
            a0 += __shfl_xor(a0,1); a1 += __shfl_xor(a1,1);
            a2 += __shfl_xor(a2,1); a3 += __shfl_xor(a3,1);
            a0 += __shfl_xor(a0,2); a1 += __shfl_xor(a1,2);
            a2 += __shfl_xor(a2,2); a3 += __shfl_xor(a3,2);
            if (q==0) *(float4*)&gpart[j0] = make_float4(a0,a1,a2,a3);
        }
        if (t < 544){
            // params = clip(h@W_p + b): 68 col-groups of 4, 8-way K-pair split
            const int g = t>>3, q = t&7, j0 = g*4;
            const int k0 = q*16;
            const h2_t* wb = wp2 + k0*PPAD + j0;
            float a0=0.f,a1=0.f,a2=0.f,a3=0.f;
            #pragma unroll 4
            for (int p=0; p<16; ++p){
                h2_t hv = hb2[k0+p];
                uint4 uu = *(const uint4*)(wb + p*PPAD);
                DOT2X4(uu, hv);
            }
            a0 += __shfl_xor(a0,1); a1 += __shfl_xor(a1,1);
            a2 += __shfl_xor(a2,1); a3 += __shfl_xor(a3,1);
            a0 += __shfl_xor(a0,2); a1 += __shfl_xor(a1,2);
            a2 += __shfl_xor(a2,2); a3 += __shfl_xor(a3,2);
            a0 += __shfl_xor(a0,4); a1 += __shfl_xor(a1,4);
            a2 += __shfl_xor(a2,4); a3 += __shfl_xor(a3,4);
            if (q==0){
                float4 bb = *(const float4*)(bpp + j0);
                float pv[4] = { clipf(a0+bb.x), clipf(a1+bb.y), clipf(a2+bb.z), clipf(a3+bb.w) };
                #pragma unroll
                for (int jj=0; jj<4; ++jj){
                    const int j = j0+jj; const float p = pv[jj];
                    if (j < 64) kv[0][j] = tanhf(p);
                    else if (j < 70) prmS[j-64] = p;
                    else if (j < 134) kv[1][j-70] = tanhf(p);
                    else if (j < 140) prmS[6 + (j-134)] = p;
                    else if (j < 204) ebuf[j-140] = sigf(p);
                    else if (j < 268) abuf[j-204] = tanhf(p);
                }
            }
        } else if (t < 800){
            // Mn: 128 rows x 2-way m-split
            const int idx = t-544, n = idx>>1, q2 = idx&1, m0 = q2*32;
            float s = 0.f;
            #pragma unroll 8
            for (int m=m0; m<m0+32; ++m){ float v=Mem[n][m]; s=fmaf(v,v,s); }
            s += __shfl_xor(s,1);
            if (q2==0) Mn[n] = sqrtf(s);
        } else if (t < 805){
            // x prefetch into xr2 pairs 32..36
            if (step+1 < T_){
                const int p = t-800;
                const int e0 = 2*p, e1 = e0+1;
                const float* xin = inputs + (b*T_ + step+1)*IN_DIM_;
                h2_t v;
                v.x = (_Float16)((e0<IN_DIM_) ? xin[e0] : 0.f);
                v.y = (_Float16)((e1<IN_DIM_) ? xin[e1] : 0.f);
                xr2[32+p] = v;
            }
        } else if (t >= 896){
            const int o = (t-896)>>4, l16 = t&15;
            float s = 0.f;
            #pragma unroll
            for (int j=0; j<16; ++j){
                const int i = l16 + (j<<4);
                s = fmaf(hbuf[i], W_o[i*OUT_ + o], s);
            }
            s += __shfl_xor(s,1); s += __shfl_xor(s,2);
            s += __shfl_xor(s,4); s += __shfl_xor(s,8);
            if (l16==0) jpart[o] = s;
        }
        __syncthreads();

        // F: inner products (all 1024, 4-way m split) + scal decode (2 threads)
        {
            const int h = t>>9, n = (t>>2)&127, q = t&3, m0 = q*16;
            float s = 0.f;
            #pragma unroll 8
            for (int m=m0; m<m0+16; ++m) s = fmaf(kv[h][m], Mem[n][m], s);
            s += __shfl_xor(s,1); s += __shfl_xor(s,2);
            if (q==0) innr[h][n] = s;
        }
        if (t < 2){
            const int h = t;
            const float* ps = prmS + 6*h;
            scal[h]   = splus(ps[0]);
            scal[2+h] = sigf(ps[1]);
            float p0=ps[2], p1=ps[3], p2=ps[4];
            float mx = fmaxf(p0, fmaxf(p1, p2));
            float e0=__expf(p0-mx), e1=__expf(p1-mx), e2=__expf(p2-mx);
            float s = e0+e1+e2;
            scal[6+3*h]=e0/s; scal[7+3*h]=e1/s; scal[8+3*h]=e2/s;
            scal[4+h] = 1.f + splus(ps[5]);
        }
        __syncthreads();

        // G: key norm + content softmax + interp + shift + sharpen (2 waves)
        if (t < 128){
            const int h = t>>6, l = ln;
            float kvl = kv[h][l];
            float kn2 = kvl*kvl;
            for (int off=32; off>=1; off>>=1) kn2 += __shfl_xor(kn2, off);
            float kn = sqrtf(kn2);
            float beta = scal[h], g = scal[2+h];
            float bk0 = beta * innr[h][l]   /(kn*Mn[l]   +1e-8f);
            float bk1 = beta * innr[h][l+64]/(kn*Mn[l+64]+1e-8f);
            float mx = fmaxf(bk0,bk1);
            for (int off=32; off>=1; off>>=1) mx = fmaxf(mx, __shfl_xor(mx, off));
            float e0=__expf(bk0-mx), e1=__expf(bk1-mx);
            float s=e0+e1;
            for (int off=32; off>=1; off>>=1) s += __shfl_xor(s, off);
            float wc0=e0/s, wc1=e1/s;
            wgs[h][l]    = g*wc0 + (1.f-g)*wtab[h][l];
            wgs[h][l+64] = g*wc1 + (1.f-g)*wtab[h][l+64];
            float gamma = scal[4+h];
            float s0=scal[6+3*h], s1=scal[7+3*h], s2=scal[8+3*h];
            const int n0=l, n1=l+64;
            float wt0 = s0*wgs[h][(n0+1)&127] + s1*wgs[h][n0] + s2*wgs[h][(n0+127)&127];
            float wt1 = s0*wgs[h][(n1+1)&127] + s1*wgs[h][n1] + s2*wgs[h][(n1+127)&127];
            float wp0 = __powf(wt0, gamma), wp1 = __powf(wt1, gamma);
            float ss = wp0+wp1;
            for (int off=32; off>=1; off>>=1) ss += __shfl_xor(ss, off);
            float inv = 1.0f/(ss+1e-8f);
            wtab[h][n0] = wp0*inv; wtab[h][n1] = wp1*inv;
        }
        __syncthreads();

        // H: memory write + fused read-head partials
        {
            const float el = ebuf[ln], al = abuf[ln];
            const int n0 = wv*8;
            float racc = 0.f;
            #pragma unroll
            for (int k=0; k<8; ++k){
                const int n = n0+k;
                float ww = wtab[1][n];
                float wr = wtab[0][n];
                float v = Mem[n][ln]*(1.0f - ww*el) + ww*al;
                Mem[n][ln] = v;
                racc = fmaf(wr, v, racc);
            }
            rpart[wv][ln] = racc;
        }
        __syncthreads();

        // J: r finalize + output (waves 0-7) ; xr2 r-pack (wave 8)
        if (t < 512){
            const int o = wv;
            float rm = 0.f;
            #pragma unroll
            for (int k=0; k<16; ++k) rm += rpart[k][ln];
            float s = rm * W_o[(U_+ln)*OUT_ + o];
            for (int off=32; off>=1; off>>=1) s += __shfl_xor(s, off);
            if (ln==0 && step>=TSTART){
                float logit = clipf(s + jpart[o] + b_o[o]);
                out[((b*(T_-TSTART)) + (step-TSTART))*OUT_ + o] = sigf(logit);
            }
        } else if (t < 576){
            float rm = 0.f;
            #pragma unroll
            for (int k=0; k<16; ++k) rm += rpart[k][ln];
            float other = __shfl_xor(rm, 1);
            if ((ln&1)==0){
                h2_t v; v.x = (_Float16)rm; v.y = (_Float16)other;
                xr2[ln>>1] = v;
            }
        }
        __syncthreads();
    }
}

extern "C" void kernel_launch(void* const* d_in, const int* in_sizes, int n_in,
                              void* d_out, int out_size, void* d_ws, size_t ws_size,
                              hipStream_t stream) {
    const float* inputs = (const float*)d_in[0];
    const float* W_x    = (const float*)d_in[1];
    const float* W_h    = (const float*)d_in[2];
    const float* b_lstm = (const float*)d_in[3];
    const float* W_p    = (const float*)d_in[4];
    const float* b_p    = (const float*)d_in[5];
    const float* W_o    = (const float*)d_in[6];
    const float* b_o    = (const float*)d_in[7];
    const float* r0     = (const float*)d_in[8];
    const float* w0     = (const float*)d_in[9];
    float* out = (float*)d_out;

    char* ws = (char*)d_ws;
    h2_t* wx2 = (h2_t*)(ws + WX2_OFF);
    h2_t* wh2 = (h2_t*)(ws + WH2_OFF);
    h2_t* wp2 = (h2_t*)(ws + WP2_OFF);
    float* blp = (float*)(ws + BLP_OFF);
    float* bpp = (float*)(ws + BPP_OFF);

    prep_kernel<<<512, 256, 0, stream>>>(W_x, W_h, W_p, b_lstm, b_p, wx2, wh2, wp2, blp, bpp);
    ntm_kernel<<<B_, 1024, 0, stream>>>(inputs, W_o, b_o, r0, w0, wx2, wh2, wp2, blp, bpp, out);
}